// Round 1
// baseline (898.567 us; speedup 1.0000x reference)
//
#include <hip/hip_runtime.h>
#include <hip/hip_bf16.h>

#define NN 32
#define CIN 64
#define TTOT 300
#define VV 25
#define PP 3
#define COUT 128
#define TTILE 5
#define NCOL 125          // TTILE*VV, padded to 128 columns in GEMM
#define NTILES 60         // TTOT / TTILE
#define ZSTRIDE 130       // Z LDS row stride (floats) — conflict-mitigating
#define CNT 240000.0f     // N*T*V per channel

// ws layout (float offsets). Total ~25216 floats ≈ 101 KB.
#define WS_STATS 0        // 256: sum[128], sumsq[128]
#define WS_SCALE 256      // 128
#define WS_SHIFT 384      // 128
#define WS_WT    512      // 3*64*128 = 24576 : W^T as [p][c][o]
#define WS_BSUM  25088    // 128

__global__ __launch_bounds__(256) void prep_kernel(const float* __restrict__ W,
                                                   const float* __restrict__ b,
                                                   float* __restrict__ ws) {
    int tid = blockIdx.x * blockDim.x + threadIdx.x;
    if (tid < 256) ws[WS_STATS + tid] = 0.0f;          // zero stats every launch
    if (tid >= 256 && tid < 384) {
        int o = tid - 256;
        ws[WS_BSUM + o] = b[o] + b[COUT + o] + b[2 * COUT + o];
    }
    if (tid < PP * CIN * COUT) {
        int o = tid % COUT;
        int c = (tid / COUT) % CIN;
        int p = tid / (COUT * CIN);
        ws[WS_WT + tid] = W[(p * COUT + o) * CIN + c]; // W^T[p][c][o]
    }
}

__global__ __launch_bounds__(512) void sgcn_main(const float* __restrict__ x,
                                                 const float* __restrict__ A,
                                                 float* __restrict__ y,
                                                 float* ws) {
    __shared__ float Zs[CIN * ZSTRIDE];   // 33.3 KB: Z_p[c][col], col in [0,128) used
    __shared__ float Wsh[CIN * COUT];     // 32 KB:   W^T_p[c][o]
    __shared__ float As[PP][VV][28];      // 8.4 KB:  A[p][w][v], row pad 28 for b128 align

    const int tid = threadIdx.x;
    const int n  = blockIdx.x / NTILES;
    const int t0 = (blockIdx.x % NTILES) * TTILE;

    // stage A once
    for (int i = tid; i < PP * VV * VV; i += 512) {
        int v = i % VV; int w = (i / VV) % VV; int p = i / (VV * VV);
        As[p][w][v] = A[i];
    }
    // zero Z pad columns 125..127 once (never rewritten; agg only writes col<125)
    if (tid < CIN * 3) {
        int c = tid / 3, col = NCOL + (tid % 3);
        Zs[c * ZSTRIDE + col] = 0.0f;
    }

    // x tile into registers: thread (c = tid>>3, t = tid&7 if <5) owns x[n,c,t0+t,0:25]
    const int cc = tid >> 3;
    const int tt = tid & 7;
    const bool active = (tt < TTILE);
    float xr[VV];
    if (active) {
        const float* xp = x + ((size_t)(n * CIN + cc) * TTOT + (t0 + tt)) * VV;
        #pragma unroll
        for (int w = 0; w < VV; ++w) xr[w] = xp[w];
    }

    const int lane = tid & 63;
    const int wave = tid >> 6;
    const int wo = wave * 16;             // 8 waves x 16 o-rows = 128

    float accA[16], accB[16];             // Y[wo+j][lane], Y[wo+j][lane+64]
    #pragma unroll
    for (int j = 0; j < 16; ++j) { accA[j] = 0.0f; accB[j] = 0.0f; }

    const float* wt = ws + WS_WT;

    for (int p = 0; p < PP; ++p) {
        __syncthreads();  // prev GEMM done before overwriting Wsh/Zs
        // stage W^T_p (coalesced)
        {
            const float* src = wt + p * (CIN * COUT);
            for (int i = tid; i < CIN * COUT; i += 512) Wsh[i] = src[i];
        }
        // aggregation: Z_p[c][t*25+v] = sum_w x[c,t,w] * A[p][w][v]
        if (active) {
            float acc[VV];
            #pragma unroll
            for (int v = 0; v < VV; ++v) acc[v] = 0.0f;
            #pragma unroll
            for (int w = 0; w < VV; ++w) {
                float xv = xr[w];
                const float* ar = &As[p][w][0];  // uniform addr -> LDS broadcast
                #pragma unroll
                for (int v = 0; v < VV; ++v) acc[v] += xv * ar[v];
            }
            float* zrow = &Zs[cc * ZSTRIDE + tt * VV];
            #pragma unroll
            for (int v = 0; v < VV; ++v) zrow[v] = acc[v];
        }
        __syncthreads();
        // GEMM slice: K=64. Per k: 2 per-lane Z reads + 4 uniform b128 W reads + 32 FMA
        #pragma unroll 4
        for (int k = 0; k < CIN; ++k) {
            float zA = Zs[k * ZSTRIDE + lane];
            float zB = Zs[k * ZSTRIDE + 64 + lane];
            const float4* wr = (const float4*)(&Wsh[k * COUT + wo]);
            float4 w0 = wr[0], w1 = wr[1], w2 = wr[2], w3 = wr[3];
            accA[0]  += w0.x * zA;  accB[0]  += w0.x * zB;
            accA[1]  += w0.y * zA;  accB[1]  += w0.y * zB;
            accA[2]  += w0.z * zA;  accB[2]  += w0.z * zB;
            accA[3]  += w0.w * zA;  accB[3]  += w0.w * zB;
            accA[4]  += w1.x * zA;  accB[4]  += w1.x * zB;
            accA[5]  += w1.y * zA;  accB[5]  += w1.y * zB;
            accA[6]  += w1.z * zA;  accB[6]  += w1.z * zB;
            accA[7]  += w1.w * zA;  accB[7]  += w1.w * zB;
            accA[8]  += w2.x * zA;  accB[8]  += w2.x * zB;
            accA[9]  += w2.y * zA;  accB[9]  += w2.y * zB;
            accA[10] += w2.z * zA;  accB[10] += w2.z * zB;
            accA[11] += w2.w * zA;  accB[11] += w2.w * zB;
            accA[12] += w3.x * zA;  accB[12] += w3.x * zB;
            accA[13] += w3.y * zA;  accB[13] += w3.y * zB;
            accA[14] += w3.z * zA;  accB[14] += w3.z * zB;
            accA[15] += w3.w * zA;  accB[15] += w3.w * zB;
        }
    }

    // epilogue: +bias, store y (pre-BN) to d_out, block-reduced stats -> atomics
    const float* bsum = ws + WS_BSUM;
    float* stats = ws + WS_STATS;
    const bool v1 = (lane < NCOL - 64);   // col1 = lane+64 valid iff lane < 61
    #pragma unroll
    for (int j = 0; j < 16; ++j) {
        int o = wo + j;
        float bj = bsum[o];
        float yA = accA[j] + bj;
        float yB = accB[j] + bj;
        float* yrow = y + (size_t)(n * COUT + o) * (TTOT * VV) + t0 * VV;
        yrow[lane] = yA;
        if (v1) yrow[64 + lane] = yB;
        float s  = yA + (v1 ? yB : 0.0f);
        float sq = yA * yA + (v1 ? yB * yB : 0.0f);
        #pragma unroll
        for (int m = 1; m < 64; m <<= 1) {
            s  += __shfl_xor(s, m, 64);
            sq += __shfl_xor(sq, m, 64);
        }
        if (lane == 0) {   // this wave exclusively owns channel o
            atomicAdd(&stats[o], s);
            atomicAdd(&stats[128 + o], sq);
        }
    }
}

__global__ void finalize_kernel(const float* __restrict__ gamma,
                                const float* __restrict__ beta,
                                float* ws) {
    int o = threadIdx.x;  // 128 threads
    float mean = ws[WS_STATS + o] * (1.0f / CNT);
    float ex2  = ws[WS_STATS + 128 + o] * (1.0f / CNT);
    float var  = ex2 - mean * mean;         // biased variance
    float rstd = rsqrtf(var + 1e-5f);
    float sc = gamma[o] * rstd;
    ws[WS_SCALE + o] = sc;
    ws[WS_SHIFT + o] = beta[o] - mean * sc;
}

__global__ __launch_bounds__(256) void norm_relu_kernel(float* __restrict__ y,
                                                        const float* __restrict__ ws) {
    const int total8 = (NN * COUT * TTOT * VV) / 8;  // 3,840,000 vectors of 8
    const float* scale = ws + WS_SCALE;
    const float* shift = ws + WS_SHIFT;
    for (int i = blockIdx.x * blockDim.x + threadIdx.x; i < total8;
         i += gridDim.x * blockDim.x) {
        size_t base = (size_t)i * 8;
        int row0 = (int)(base / 7500);           // row = n*128 + o (7500 = T*V)
        int row1 = (int)((base + 7) / 7500);
        int o0 = row0 & 127, o1 = row1 & 127;
        float s0 = scale[o0], h0 = shift[o0];
        float s1 = scale[o1], h1 = shift[o1];
        size_t bnd = (size_t)(row0 + 1) * 7500;
        float4 a = *(const float4*)(y + base);
        float4 b = *(const float4*)(y + base + 4);
        float vals[8] = {a.x, a.y, a.z, a.w, b.x, b.y, b.z, b.w};
        #pragma unroll
        for (int e = 0; e < 8; ++e) {
            bool first = (base + (size_t)e) < bnd;
            float s = first ? s0 : s1;
            float h = first ? h0 : h1;
            vals[e] = fmaxf(vals[e] * s + h, 0.0f);
        }
        a = make_float4(vals[0], vals[1], vals[2], vals[3]);
        b = make_float4(vals[4], vals[5], vals[6], vals[7]);
        *(float4*)(y + base) = a;
        *(float4*)(y + base + 4) = b;
    }
}

extern "C" void kernel_launch(void* const* d_in, const int* in_sizes, int n_in,
                              void* d_out, int out_size, void* d_ws, size_t ws_size,
                              hipStream_t stream) {
    const float* x     = (const float*)d_in[0];
    const float* A     = (const float*)d_in[1];
    const float* W     = (const float*)d_in[2];
    const float* b     = (const float*)d_in[3];
    const float* gamma = (const float*)d_in[4];
    const float* beta  = (const float*)d_in[5];
    float* y  = (float*)d_out;
    float* ws = (float*)d_ws;   // needs ~101 KB

    prep_kernel<<<96, 256, 0, stream>>>(W, b, ws);
    sgcn_main<<<NN * NTILES, 512, 0, stream>>>(x, A, y, ws);
    finalize_kernel<<<1, 128, 0, stream>>>(gamma, beta, ws);
    norm_relu_kernel<<<2048, 256, 0, stream>>>(y, ws);
}

// Round 2
// 137.425 us; speedup vs baseline: 6.5386x; 6.5386x over previous
//
#include <hip/hip_runtime.h>
#include <hip/hip_bf16.h>

#define NN 32
#define CIN 64
#define TTOT 300
#define VV 25
#define PP 3
#define COUT 128
#define TTILE 5
#define NTILES 60
#define CNT 240000.0f

// LDS strides in shorts (bf16)
#define XSTR 40      // X[t][c][w] w-stride: 80B rows -> 2-way banks, 16B aligned
#define ZSTR 72      // Z2[col'][c] c-stride: 144B rows -> 2-way banks, 16B aligned
#define NCOLP 160    // 5 t * 32 padded cols

// ws float offsets
#define WS_STATS 0    // 256 f32: sum[128], sumsq[128]
#define WS_SCALE 256  // 128 f32
#define WS_SHIFT 384  // 128 f32
#define WS_BSUM  512  // 128 f32
#define WS_W2    640  // bf16[128*192] = 12288 f32 slots; W2[o][p*64+c]

typedef float f32x4 __attribute__((ext_vector_type(4)));
typedef short s16x8 __attribute__((ext_vector_type(8)));

__device__ __forceinline__ short f2bf(float f) {
    unsigned u = __float_as_uint(f);
    u += 0x7fff + ((u >> 16) & 1);          // RNE
    return (short)(u >> 16);
}

__global__ __launch_bounds__(256) void prep_kernel(const float* __restrict__ W,
                                                   const float* __restrict__ b,
                                                   float* __restrict__ ws) {
    int tid = blockIdx.x * blockDim.x + threadIdx.x;
    if (tid < 256) ws[WS_STATS + tid] = 0.0f;               // zero stats every launch
    if (tid >= 256 && tid < 384) {
        int o = tid - 256;
        ws[WS_BSUM + o] = b[o] + b[COUT + o] + b[2 * COUT + o];
    }
    if (tid < COUT * 192) {                                  // W2[o][k], k = p*64+c
        int o = tid / 192, k = tid % 192;
        int p = k / 64, c = k % 64;
        ((short*)(ws + WS_W2))[tid] = f2bf(W[(p * COUT + o) * CIN + c]);
    }
}

__global__ __launch_bounds__(512, 4) void sgcn_main(const float* __restrict__ x,
                                                    const float* __restrict__ A,
                                                    float* __restrict__ y,
                                                    float* ws) {
    __shared__ __align__(16) short Xs[TTILE * 64 * XSTR];   // 25600 B
    __shared__ __align__(16) short Ats[PP * 32 * XSTR];     // 7680 B  (zero-padded)
    __shared__ __align__(16) short Z2s[NCOLP * ZSTR];       // 23040 B
    __shared__ float sstat[256];                            // 1024 B

    const int tid  = threadIdx.x;
    const int lane = tid & 63;
    const int wave = tid >> 6;
    const int n  = blockIdx.x / NTILES;
    const int t0 = (blockIdx.x % NTILES) * TTILE;
    const int lg = lane >> 4;      // lane group 0..3 (k-block)
    const int li = lane & 15;      // row/col within fragment

    // ---- zero At (pads MUST be 0: they are the K/M padding) and sstat ----
    {
        int* az = (int*)Ats;
        #pragma unroll
        for (int i = 0; i < 4; ++i) {
            int idx = tid + i * 512;
            if (idx < PP * 32 * XSTR / 2) az[idx] = 0;
        }
        if (tid < 256) sstat[tid] = 0.0f;
    }
    __syncthreads();

    // ---- stage X rows: X[t][c][w] = bf16(x[n,c,t0+t,w]), w>=25 zeroed ----
    if (tid < 320) {
        int c = tid / 5, t = tid % 5;
        const float* xp = x + ((size_t)(n * CIN + c) * TTOT + (t0 + t)) * VV;
        short* dst = &Xs[(t * 64 + c) * XSTR];
        #pragma unroll
        for (int g = 0; g < 5; ++g) {
            s16x8 v;
            #pragma unroll
            for (int e = 0; e < 8; ++e) {
                int w = g * 8 + e;
                v[e] = (w < VV) ? f2bf(xp[w]) : (short)0;
            }
            *(s16x8*)(dst + g * 8) = v;
        }
    }
    // ---- stage At: At[p][v][w] = bf16(A[p][w][v]) (transpose) ----
    for (int i = tid; i < PP * VV * VV; i += 512) {
        int v = i % VV, w = (i / VV) % VV, p = i / (VV * VV);
        Ats[(p * 32 + v) * XSTR + w] = f2bf(A[i]);
    }
    __syncthreads();

    // ---- wave tiling for conv: 4 o-groups x 2 col-groups ----
    const int ow = wave >> 1;          // 0..3 -> o0 = ow*32 (2 m-frags)
    const int cw = wave & 1;           // 0..1 -> cols cw*80 .. +80 (5 col-frags)
    const int o0 = ow * 32;
    const short* w2 = (const short*)(ws + WS_W2);

    f32x4 acc[2][5];
    #pragma unroll
    for (int mf = 0; mf < 2; ++mf)
        #pragma unroll
        for (int cf = 0; cf < 5; ++cf)
            acc[mf][cf] = (f32x4){0.f, 0.f, 0.f, 0.f};

    for (int p = 0; p < PP; ++p) {
        // prefetch this p's W fragments (global, L2-hot; latency hides under agg)
        s16x8 wf[2][2];
        #pragma unroll
        for (int mf = 0; mf < 2; ++mf)
            #pragma unroll
            for (int ks = 0; ks < 2; ++ks)
                wf[mf][ks] = *(const s16x8*)(w2 + (o0 + mf * 16 + li) * 192
                                                + p * 64 + ks * 32 + lg * 8);

        // aggregation: Z_p^T[v][c] per t; 40 frags -> 5 per wave, 1 MFMA each (K=32)
        #pragma unroll
        for (int q = 0; q < 5; ++q) {
            int f = wave * 5 + q;            // 0..39
            int t = f >> 3, rem = f & 7;
            int vf = rem >> 2, cfr = rem & 3;
            s16x8 af = *(const s16x8*)(&Ats[(p * 32 + vf * 16 + li) * XSTR + lg * 8]);
            s16x8 bf = *(const s16x8*)(&Xs[(t * 64 + cfr * 16 + li) * XSTR + lg * 8]);
            f32x4 z = (f32x4){0.f, 0.f, 0.f, 0.f};
            f32x4 d = __builtin_amdgcn_mfma_f32_16x16x32_bf16(af, bf, z, 0, 0, 0);
            int brow = t * 32 + vf * 16 + lg * 4;   // col' row in Z2
            int ccol = cfr * 16 + li;               // c
            #pragma unroll
            for (int r = 0; r < 4; ++r)
                Z2s[(brow + r) * ZSTR + ccol] = f2bf(d[r]);
        }
        __syncthreads();

        // conv accumulate: acc[o-frag][col-frag] += W_p * Z_p  (K=64: 2 K-steps)
        #pragma unroll
        for (int cf = 0; cf < 5; ++cf) {
            int col0 = cw * 80 + cf * 16;
            #pragma unroll
            for (int ks = 0; ks < 2; ++ks) {
                s16x8 zf = *(const s16x8*)(&Z2s[(col0 + li) * ZSTR + ks * 32 + lg * 8]);
                #pragma unroll
                for (int mf = 0; mf < 2; ++mf)
                    acc[mf][cf] = __builtin_amdgcn_mfma_f32_16x16x32_bf16(
                        wf[mf][ks], zf, acc[mf][cf], 0, 0, 0);
            }
        }
        __syncthreads();   // protect Z2 before next p's aggregation overwrites
    }

    // ---- epilogue: +bias, store y, per-channel stats (shfl -> LDS -> global) ----
    const float* bsum = ws + WS_BSUM;
    #pragma unroll
    for (int mf = 0; mf < 2; ++mf) {
        #pragma unroll
        for (int r = 0; r < 4; ++r) {
            int o = o0 + mf * 16 + lg * 4 + r;
            float bo = bsum[o];
            float s = 0.f, sq = 0.f;
            #pragma unroll
            for (int cf = 0; cf < 5; ++cf) {
                int colp = cw * 80 + cf * 16 + li;   // padded col' = t*32 + v
                int t = colp >> 5, v = colp & 31;
                float val = acc[mf][cf][r] + bo;
                if (v < VV) {
                    y[((size_t)(n * COUT + o) * TTOT + (t0 + t)) * VV + v] = val;
                    s += val; sq += val * val;
                }
            }
            #pragma unroll
            for (int m = 1; m < 16; m <<= 1) {
                s  += __shfl_xor(s, m, 64);
                sq += __shfl_xor(sq, m, 64);
            }
            if (li == 0) {
                atomicAdd(&sstat[o], s);
                atomicAdd(&sstat[128 + o], sq);
            }
        }
    }
    __syncthreads();
    if (tid < 256) atomicAdd(&ws[WS_STATS + tid], sstat[tid]);
}

__global__ void finalize_kernel(const float* __restrict__ gamma,
                                const float* __restrict__ beta,
                                float* ws) {
    int o = threadIdx.x;  // 128 threads
    float mean = ws[WS_STATS + o] * (1.0f / CNT);
    float ex2  = ws[WS_STATS + 128 + o] * (1.0f / CNT);
    float var  = ex2 - mean * mean;
    float rstd = rsqrtf(var + 1e-5f);
    float sc = gamma[o] * rstd;
    ws[WS_SCALE + o] = sc;
    ws[WS_SHIFT + o] = beta[o] - mean * sc;
}

__global__ __launch_bounds__(256) void norm_relu_kernel(float* __restrict__ y,
                                                        const float* __restrict__ ws) {
    const int total8 = (NN * COUT * TTOT * VV) / 8;
    const float* scale = ws + WS_SCALE;
    const float* shift = ws + WS_SHIFT;
    for (int i = blockIdx.x * blockDim.x + threadIdx.x; i < total8;
         i += gridDim.x * blockDim.x) {
        size_t base = (size_t)i * 8;
        int row0 = (int)(base / 7500);
        int row1 = (int)((base + 7) / 7500);
        int o0 = row0 & 127, o1 = row1 & 127;
        float s0 = scale[o0], h0 = shift[o0];
        float s1 = scale[o1], h1 = shift[o1];
        size_t bnd = (size_t)(row0 + 1) * 7500;
        float4 a = *(const float4*)(y + base);
        float4 b = *(const float4*)(y + base + 4);
        float vals[8] = {a.x, a.y, a.z, a.w, b.x, b.y, b.z, b.w};
        #pragma unroll
        for (int e = 0; e < 8; ++e) {
            bool first = (base + (size_t)e) < bnd;
            float s = first ? s0 : s1;
            float h = first ? h0 : h1;
            vals[e] = fmaxf(vals[e] * s + h, 0.0f);
        }
        a = make_float4(vals[0], vals[1], vals[2], vals[3]);
        b = make_float4(vals[4], vals[5], vals[6], vals[7]);
        *(float4*)(y + base) = a;
        *(float4*)(y + base + 4) = b;
    }
}

extern "C" void kernel_launch(void* const* d_in, const int* in_sizes, int n_in,
                              void* d_out, int out_size, void* d_ws, size_t ws_size,
                              hipStream_t stream) {
    const float* x     = (const float*)d_in[0];
    const float* A     = (const float*)d_in[1];
    const float* W     = (const float*)d_in[2];
    const float* b     = (const float*)d_in[3];
    const float* gamma = (const float*)d_in[4];
    const float* beta  = (const float*)d_in[5];
    float* y  = (float*)d_out;
    float* ws = (float*)d_ws;   // ~52 KB used

    prep_kernel<<<96, 256, 0, stream>>>(W, b, ws);
    sgcn_main<<<NN * NTILES, 512, 0, stream>>>(x, A, y, ws);
    finalize_kernel<<<1, 128, 0, stream>>>(gamma, beta, ws);
    norm_relu_kernel<<<2048, 256, 0, stream>>>(y, ws);
}